// Round 1
// baseline (4538.862 us; speedup 1.0000x reference)
//
#include <hip/hip_runtime.h>

// PureCartesianTensorProductO3Sparse on MI355X (gfx950), fp32 vector-ALU.
// Block = 256 threads = 16 rows x 16 output channels (o).
// Wave layout: lane = r(16) + 16*o_sub(4); o = wave*4 + o_sub  -> weight LDS
// reads are 16-lane broadcasts across 4 conflict-free bank quads.
// Weights staged in LDS in 3 phases of 2 matrices (60.4 KB total LDS -> 2 blocks/CU).

constexpr int TILE_R  = 16;
constexpr int NTHR    = 256;
constexpr int WSTRIDE = 260;            // 256 + 4 pad floats per o-slice (bank stagger)
constexpr int WSLICE  = 16 * WSTRIDE;   // 4160 floats per path matrix
constexpr int RSTRIDE = 212;            // 208 + 4 pad floats per staged input row

__device__ __forceinline__ float dot16(const float* __restrict__ w, const float* a) {
    float s0 = 0.f, s1 = 0.f, s2 = 0.f, s3 = 0.f;
#pragma unroll
    for (int k = 0; k < 4; ++k) {
        float4 v = *(const float4*)(w + 4 * k);
        s0 = fmaf(v.x, a[4 * k + 0], s0);
        s1 = fmaf(v.y, a[4 * k + 1], s1);
        s2 = fmaf(v.z, a[4 * k + 2], s2);
        s3 = fmaf(v.w, a[4 * k + 3], s3);
    }
    return (s0 + s1) + (s2 + s3);
}

// Load two 16x16x16 path matrices into LDS; optionally transpose (a,b)->(b,a).
__device__ __forceinline__ void load_w2(const float* __restrict__ wgt, float* ws,
                                        int p0, bool t0, int p1, bool t1, int tid) {
#pragma unroll 4
    for (int s = tid; s < 8192; s += NTHR) {
        int  m    = s >> 12;            // which of the two matrices (wave-uniform)
        int  rem  = s & 4095;
        int  a    = (rem >> 4) & 15;
        int  b    = rem & 15;
        int  oo   = rem >> 8;
        int  path = m ? p1 : p0;
        bool tr   = m ? t1 : t0;
        float v   = wgt[path * 4096 + rem];     // coalesced, L2-resident
        int  off  = tr ? (b * 16 + a) : (a * 16 + b);
        ws[m * WSLICE + oo * WSTRIDE + off] = v;
    }
}

__global__ __launch_bounds__(NTHR, 2)
void tp_kernel(const float* __restrict__ x1, const float* __restrict__ x2,
               const float* __restrict__ wgt, float* __restrict__ out, int N)
{
    __shared__ float Ws[2 * WSLICE];          // 33280 B
    __shared__ float As[TILE_R * RSTRIDE];    // 13568 B
    __shared__ float Bs[TILE_R * RSTRIDE];    // 13568 B  -> 60416 B total

    const int tid  = threadIdx.x;
    const int wave = tid >> 6;
    const int lane = tid & 63;
    const int o    = (wave << 2) + (lane >> 4);   // 0..15
    const int r    = lane & 15;                   // 0..15
    const long long row0 = (long long)blockIdx.x * TILE_R;

    // ---- stage input tile: first 208 floats of each 416-float row ----
    for (int idx = tid; idx < TILE_R * 52; idx += NTHR) {
        int rr = idx / 52, cc = idx - rr * 52;
        float4 va = make_float4(0.f, 0.f, 0.f, 0.f), vb = va;
        if (row0 + rr < N) {
            long long g = (row0 + rr) * 416 + cc * 4;
            va = *(const float4*)(x1 + g);
            vb = *(const float4*)(x2 + g);
        }
        *(float4*)&As[rr * RSTRIDE + cc * 4] = va;
        *(float4*)&Bs[rr * RSTRIDE + cc * 4] = vb;
    }
    load_w2(wgt, Ws, 0, true, 1, true, tid);   // W0^T, W1^T  ([o][b][a])
    __syncthreads();

    // ---- register caches: A0, B0, B1 ----
    float a0[16], b0[16], b1[48];
#pragma unroll
    for (int k = 0; k < 4; ++k) {
        float4 v = *(const float4*)&As[r * RSTRIDE + 4 * k];
        a0[4*k+0] = v.x; a0[4*k+1] = v.y; a0[4*k+2] = v.z; a0[4*k+3] = v.w;
        float4 u = *(const float4*)&Bs[r * RSTRIDE + 4 * k];
        b0[4*k+0] = u.x; b0[4*k+1] = u.y; b0[4*k+2] = u.z; b0[4*k+3] = u.w;
    }
#pragma unroll
    for (int k = 0; k < 12; ++k) {
        float4 v = *(const float4*)&Bs[r * RSTRIDE + 16 + 4 * k];
        b1[4*k+0] = v.x; b1[4*k+1] = v.y; b1[4*k+2] = v.z; b1[4*k+3] = v.w;
    }

    float o0 = 0.f, o1[3] = {0.f, 0.f, 0.f};
    float o2[9] = {0.f,0.f,0.f,0.f,0.f,0.f,0.f,0.f,0.f};

    // ---- phase A: paths (0,0) and (0,1) ----
    {
        const float* w0 = &Ws[o * WSTRIDE];            // W0^T[o][b][a]
        const float* w1 = &Ws[WSLICE + o * WSTRIDE];   // W1^T[o][b][a]
#pragma unroll
        for (int b = 0; b < 16; ++b) {
            float t0 = dot16(w0 + 16 * b, a0);         // sum_a W0[o,a,b] A0[a]
            float t1 = dot16(w1 + 16 * b, a0);
            o0    = fmaf(t0, b0[b], o0);
            o1[0] = fmaf(t1, b1[3*b+0], o1[0]);
            o1[1] = fmaf(t1, b1[3*b+1], o1[1]);
            o1[2] = fmaf(t1, b1[3*b+2], o1[2]);
        }
    }
    __syncthreads();
    load_w2(wgt, Ws, 2, true, 3, false, tid);  // W2^T, W3
    __syncthreads();

    // ---- phase B: paths (0,2) and (1,0) ----
    {
        const float* w2 = &Ws[o * WSTRIDE];            // W2^T[o][b][a]
        const float* w3 = &Ws[WSLICE + o * WSTRIDE];   // W3[o][a][b]
#pragma unroll
        for (int b = 0; b < 16; ++b) {
            float t = dot16(w2 + 16 * b, a0);          // sum_a W2[o,a,b] A0[a]
            const float* b2 = &Bs[r * RSTRIDE + 64 + 9 * b];
#pragma unroll
            for (int k = 0; k < 9; ++k) o2[k] = fmaf(t, b2[k], o2[k]);
        }
#pragma unroll
        for (int a = 0; a < 16; ++a) {
            float u = dot16(w3 + 16 * a, b0);          // sum_b W3[o,a,b] B0[b]
            const float* a1 = &As[r * RSTRIDE + 16 + 3 * a];
            o1[0] = fmaf(u, a1[0], o1[0]);
            o1[1] = fmaf(u, a1[1], o1[1]);
            o1[2] = fmaf(u, a1[2], o1[2]);
        }
    }
    __syncthreads();
    load_w2(wgt, Ws, 4, false, 5, false, tid); // W4, W5
    __syncthreads();

    // ---- phase C: paths (1,1) and (2,0) ----
    {
        const float* w4 = &Ws[o * WSTRIDE];            // W4[o][a][b]
        const float* w5 = &Ws[WSLICE + o * WSTRIDE];   // W5[o][a][b]
#pragma unroll
        for (int a = 0; a < 16; ++a) {
            const float* wa = w4 + 16 * a;
            float v0 = 0.f, v1 = 0.f, v2 = 0.f;        // v_j = sum_b W4[o,a,b] B1[b,j]
#pragma unroll
            for (int k = 0; k < 4; ++k) {
                float4 w = *(const float4*)(wa + 4 * k);
                v0 = fmaf(w.x, b1[12*k+0], v0); v1 = fmaf(w.x, b1[12*k+ 1], v1); v2 = fmaf(w.x, b1[12*k+ 2], v2);
                v0 = fmaf(w.y, b1[12*k+3], v0); v1 = fmaf(w.y, b1[12*k+ 4], v1); v2 = fmaf(w.y, b1[12*k+ 5], v2);
                v0 = fmaf(w.z, b1[12*k+6], v0); v1 = fmaf(w.z, b1[12*k+ 7], v1); v2 = fmaf(w.z, b1[12*k+ 8], v2);
                v0 = fmaf(w.w, b1[12*k+9], v0); v1 = fmaf(w.w, b1[12*k+10], v1); v2 = fmaf(w.w, b1[12*k+11], v2);
            }
            const float* a1 = &As[r * RSTRIDE + 16 + 3 * a];
            float a10 = a1[0], a11 = a1[1], a12 = a1[2];
            o2[0] = fmaf(a10, v0, o2[0]); o2[1] = fmaf(a10, v1, o2[1]); o2[2] = fmaf(a10, v2, o2[2]);
            o2[3] = fmaf(a11, v0, o2[3]); o2[4] = fmaf(a11, v1, o2[4]); o2[5] = fmaf(a11, v2, o2[5]);
            o2[6] = fmaf(a12, v0, o2[6]); o2[7] = fmaf(a12, v1, o2[7]); o2[8] = fmaf(a12, v2, o2[8]);
        }
#pragma unroll
        for (int a = 0; a < 16; ++a) {
            float u = dot16(w5 + 16 * a, b0);          // sum_b W5[o,a,b] B0[b]
            const float* a2 = &As[r * RSTRIDE + 64 + 9 * a];
#pragma unroll
            for (int k = 0; k < 9; ++k) o2[k] = fmaf(u, a2[k], o2[k]);
        }
    }

    // ---- store: 13 computed floats + cooperative zero fill of cols 208..415 ----
    if (row0 + r < N) {
        long long ob = (row0 + r) * 416;
        out[ob + o] = o0;
        out[ob + 16 + 3*o + 0] = o1[0];
        out[ob + 16 + 3*o + 1] = o1[1];
        out[ob + 16 + 3*o + 2] = o1[2];
#pragma unroll
        for (int k = 0; k < 9; ++k) out[ob + 64 + 9*o + k] = o2[k];
        float4 z = make_float4(0.f, 0.f, 0.f, 0.f);
#pragma unroll
        for (int k = o; k < 52; k += 16) *(float4*)&out[ob + 208 + 4*k] = z;
    }
}

extern "C" void kernel_launch(void* const* d_in, const int* in_sizes, int n_in,
                              void* d_out, int out_size, void* d_ws, size_t ws_size,
                              hipStream_t stream) {
    const float* x1  = (const float*)d_in[0];
    const float* x2  = (const float*)d_in[1];
    const float* wgt = (const float*)d_in[2];
    float* out = (float*)d_out;
    const int N = in_sizes[0] / 416;
    const int grid = (N + TILE_R - 1) / TILE_R;
    hipLaunchKernelGGL(tp_kernel, dim3(grid), dim3(NTHR), 0, stream, x1, x2, wgt, out, N);
}

// Round 2
// 987.206 us; speedup vs baseline: 4.5977x; 4.5977x over previous
//
#include <hip/hip_runtime.h>

// PureCartesianTensorProductO3Sparse on MI355X (gfx950), fp32 vector-ALU.
// Block = 256 threads = 16 rows x 16 output channels (o).
// Wave layout: lane = r(16) + 16*o_sub(4); o = wave*4 + o_sub -> weight LDS
// reads are 16-lane broadcasts across 4 bank quads (WSTRIDE%32==4 stagger).
// R2 changes vs R1:
//  * All weights kept in NATURAL [o][a][b] layout (no transpose) -> staging
//    copy is conflict-free; paths re-derived to contract in that layout.
//  * Epilogue stages results in LDS and writes all 416 floats/row with flat
//    coalesced float4 stores (R1's scattered scalar stores caused 23x write
//    amplification via partial-cache-line RMW).

constexpr int TILE_R  = 16;
constexpr int NTHR    = 256;
constexpr int WSTRIDE = 260;            // 256 + 4 pad floats per o-slice
constexpr int WSLICE  = 16 * WSTRIDE;   // floats per path matrix in LDS
constexpr int RSTRIDE = 212;            // 208 + 4 pad floats per staged row

__device__ __forceinline__ float dot16(const float* __restrict__ w, const float* a) {
    float s0 = 0.f, s1 = 0.f, s2 = 0.f, s3 = 0.f;
#pragma unroll
    for (int k = 0; k < 4; ++k) {
        float4 v = *(const float4*)(w + 4 * k);
        s0 = fmaf(v.x, a[4 * k + 0], s0);
        s1 = fmaf(v.y, a[4 * k + 1], s1);
        s2 = fmaf(v.z, a[4 * k + 2], s2);
        s3 = fmaf(v.w, a[4 * k + 3], s3);
    }
    return (s0 + s1) + (s2 + s3);
}

// t[b] += sum_a W[o,a,b] * a0[a], natural [a][b] layout (16 accumulators).
__device__ __forceinline__ void accum_t(const float* __restrict__ w,
                                        const float* a0, float* t) {
#pragma unroll
    for (int a = 0; a < 16; ++a) {
        float av = a0[a];
        const float* wr = w + 16 * a;
#pragma unroll
        for (int k = 0; k < 4; ++k) {
            float4 v = *(const float4*)(wr + 4 * k);
            t[4*k+0] = fmaf(v.x, av, t[4*k+0]);
            t[4*k+1] = fmaf(v.y, av, t[4*k+1]);
            t[4*k+2] = fmaf(v.z, av, t[4*k+2]);
            t[4*k+3] = fmaf(v.w, av, t[4*k+3]);
        }
    }
}

// Copy two 16x16x16 path matrices into LDS (natural layout, float4 both sides).
__device__ __forceinline__ void load_w2(const float* __restrict__ wgt, float* ws,
                                        int p0, int p1, int tid) {
#pragma unroll
    for (int s = tid; s < 2048; s += NTHR) {
        int m   = s >> 10;                 // which matrix (wave-uniform)
        int rem = s & 1023;                // float4 index within matrix
        int oo  = rem >> 6;
        int off = (rem & 63) << 2;
        float4 v = *(const float4*)(wgt + (m ? p1 : p0) * 4096 + (rem << 2));
        *(float4*)&ws[m * WSLICE + oo * WSTRIDE + off] = v;
    }
}

__global__ __launch_bounds__(NTHR, 2)
void tp_kernel(const float* __restrict__ x1, const float* __restrict__ x2,
               const float* __restrict__ wgt, float* __restrict__ out, int N)
{
    __shared__ float Ws[2 * WSLICE];          // 33280 B
    __shared__ float As[TILE_R * RSTRIDE];    // 13568 B (inputs, then output stage)
    __shared__ float Bs[TILE_R * RSTRIDE];    // 13568 B  -> 60416 B total

    const int tid  = threadIdx.x;
    const int wave = tid >> 6;
    const int lane = tid & 63;
    const int o    = (wave << 2) + (lane >> 4);   // 0..15
    const int r    = lane & 15;                   // 0..15
    const long long row0 = (long long)blockIdx.x * TILE_R;

    // ---- stage input tile: first 208 floats of each 416-float row ----
    for (int idx = tid; idx < TILE_R * 52; idx += NTHR) {
        int rr = idx / 52, cc = idx - rr * 52;
        float4 va = make_float4(0.f, 0.f, 0.f, 0.f), vb = va;
        if (row0 + rr < N) {
            long long g = (row0 + rr) * 416 + cc * 4;
            va = *(const float4*)(x1 + g);
            vb = *(const float4*)(x2 + g);
        }
        *(float4*)&As[rr * RSTRIDE + cc * 4] = va;
        *(float4*)&Bs[rr * RSTRIDE + cc * 4] = vb;
    }
    load_w2(wgt, Ws, 0, 1, tid);
    __syncthreads();

    // ---- register caches: A0, B0, B1 ----
    float a0[16], b0[16], b1[48];
#pragma unroll
    for (int k = 0; k < 4; ++k) {
        float4 v = *(const float4*)&As[r * RSTRIDE + 4 * k];
        a0[4*k+0] = v.x; a0[4*k+1] = v.y; a0[4*k+2] = v.z; a0[4*k+3] = v.w;
        float4 u = *(const float4*)&Bs[r * RSTRIDE + 4 * k];
        b0[4*k+0] = u.x; b0[4*k+1] = u.y; b0[4*k+2] = u.z; b0[4*k+3] = u.w;
    }
#pragma unroll
    for (int k = 0; k < 12; ++k) {
        float4 v = *(const float4*)&Bs[r * RSTRIDE + 16 + 4 * k];
        b1[4*k+0] = v.x; b1[4*k+1] = v.y; b1[4*k+2] = v.z; b1[4*k+3] = v.w;
    }

    float o0 = 0.f, o1[3] = {0.f, 0.f, 0.f};
    float o2[9] = {0.f,0.f,0.f,0.f,0.f,0.f,0.f,0.f,0.f};

    // ---- phase A: paths (0,0) and (0,1) ----
    {
        const float* w0 = &Ws[o * WSTRIDE];
#pragma unroll
        for (int a = 0; a < 16; ++a)                 // o0 = sum_a A0[a]*dot_b(W0[a,:],B0)
            o0 = fmaf(a0[a], dot16(w0 + 16 * a, b0), o0);

        const float* w1 = &Ws[WSLICE + o * WSTRIDE];
        float t[16] = {0.f,0.f,0.f,0.f,0.f,0.f,0.f,0.f,0.f,0.f,0.f,0.f,0.f,0.f,0.f,0.f};
        accum_t(w1, a0, t);                          // t[b] = sum_a W1[a,b]A0[a]
#pragma unroll
        for (int b = 0; b < 16; ++b) {
            o1[0] = fmaf(t[b], b1[3*b+0], o1[0]);
            o1[1] = fmaf(t[b], b1[3*b+1], o1[1]);
            o1[2] = fmaf(t[b], b1[3*b+2], o1[2]);
        }
    }
    __syncthreads();
    load_w2(wgt, Ws, 2, 3, tid);
    __syncthreads();

    // ---- phase B: paths (0,2) and (1,0) ----
    {
        const float* w2 = &Ws[o * WSTRIDE];
        float t[16] = {0.f,0.f,0.f,0.f,0.f,0.f,0.f,0.f,0.f,0.f,0.f,0.f,0.f,0.f,0.f,0.f};
        accum_t(w2, a0, t);                          // t[b] = sum_a W2[a,b]A0[a]
#pragma unroll
        for (int b = 0; b < 16; ++b) {
            const float* b2 = &Bs[r * RSTRIDE + 64 + 9 * b];
#pragma unroll
            for (int k = 0; k < 9; ++k) o2[k] = fmaf(t[b], b2[k], o2[k]);
        }

        const float* w3 = &Ws[WSLICE + o * WSTRIDE];
#pragma unroll
        for (int a = 0; a < 16; ++a) {
            float u = dot16(w3 + 16 * a, b0);        // sum_b W3[a,b]B0[b]
            const float* a1 = &As[r * RSTRIDE + 16 + 3 * a];
            o1[0] = fmaf(u, a1[0], o1[0]);
            o1[1] = fmaf(u, a1[1], o1[1]);
            o1[2] = fmaf(u, a1[2], o1[2]);
        }
    }
    __syncthreads();
    load_w2(wgt, Ws, 4, 5, tid);
    __syncthreads();

    // ---- phase C: paths (1,1) and (2,0) ----
    {
        const float* w4 = &Ws[o * WSTRIDE];
#pragma unroll
        for (int a = 0; a < 16; ++a) {
            const float* wa = w4 + 16 * a;
            float v0 = 0.f, v1 = 0.f, v2 = 0.f;      // v_j = sum_b W4[a,b]B1[b,j]
#pragma unroll
            for (int k = 0; k < 4; ++k) {
                float4 w = *(const float4*)(wa + 4 * k);
                v0 = fmaf(w.x, b1[12*k+0], v0); v1 = fmaf(w.x, b1[12*k+ 1], v1); v2 = fmaf(w.x, b1[12*k+ 2], v2);
                v0 = fmaf(w.y, b1[12*k+3], v0); v1 = fmaf(w.y, b1[12*k+ 4], v1); v2 = fmaf(w.y, b1[12*k+ 5], v2);
                v0 = fmaf(w.z, b1[12*k+6], v0); v1 = fmaf(w.z, b1[12*k+ 7], v1); v2 = fmaf(w.z, b1[12*k+ 8], v2);
                v0 = fmaf(w.w, b1[12*k+9], v0); v1 = fmaf(w.w, b1[12*k+10], v1); v2 = fmaf(w.w, b1[12*k+11], v2);
            }
            const float* a1 = &As[r * RSTRIDE + 16 + 3 * a];
            float a10 = a1[0], a11 = a1[1], a12 = a1[2];
            o2[0] = fmaf(a10, v0, o2[0]); o2[1] = fmaf(a10, v1, o2[1]); o2[2] = fmaf(a10, v2, o2[2]);
            o2[3] = fmaf(a11, v0, o2[3]); o2[4] = fmaf(a11, v1, o2[4]); o2[5] = fmaf(a11, v2, o2[5]);
            o2[6] = fmaf(a12, v0, o2[6]); o2[7] = fmaf(a12, v1, o2[7]); o2[8] = fmaf(a12, v2, o2[8]);
        }

        const float* w5 = &Ws[WSLICE + o * WSTRIDE];
#pragma unroll
        for (int a = 0; a < 16; ++a) {
            float u = dot16(w5 + 16 * a, b0);        // sum_b W5[a,b]B0[b]
            const float* a2 = &As[r * RSTRIDE + 64 + 9 * a];
#pragma unroll
            for (int k = 0; k < 9; ++k) o2[k] = fmaf(u, a2[k], o2[k]);
        }
    }

    // ---- epilogue: stage results in LDS, then coalesced float4 stores ----
    __syncthreads();                                  // done reading As
    {
        float* dst = &As[r * RSTRIDE];
        dst[o] = o0;
        dst[16 + 3*o + 0] = o1[0];
        dst[16 + 3*o + 1] = o1[1];
        dst[16 + 3*o + 2] = o1[2];
#pragma unroll
        for (int k = 0; k < 9; ++k) dst[64 + 9*o + k] = o2[k];
    }
    __syncthreads();
    for (int idx = tid; idx < TILE_R * 104; idx += NTHR) {
        int rr = idx / 104, cc = idx - rr * 104;      // cc in float4 units (0..103)
        if (row0 + rr < N) {
            float4 v = make_float4(0.f, 0.f, 0.f, 0.f);
            if (cc < 52) v = *(const float4*)&As[rr * RSTRIDE + (cc << 2)];
            *(float4*)&out[(row0 + rr) * 416 + (cc << 2)] = v;
        }
    }
}

extern "C" void kernel_launch(void* const* d_in, const int* in_sizes, int n_in,
                              void* d_out, int out_size, void* d_ws, size_t ws_size,
                              hipStream_t stream) {
    const float* x1  = (const float*)d_in[0];
    const float* x2  = (const float*)d_in[1];
    const float* wgt = (const float*)d_in[2];
    float* out = (float*)d_out;
    const int N = in_sizes[0] / 416;
    const int grid = (N + TILE_R - 1) / TILE_R;
    hipLaunchKernelGGL(tp_kernel, dim3(grid), dim3(NTHR), 0, stream, x1, x2, wgt, out, N);
}